// Round 10
// baseline (146.925 us; speedup 1.0000x reference)
//
#include <hip/hip_runtime.h>
#include <cstdint>

#pragma clang fp contract(off)

#define BS   128
#define NQ   900
#define NC   91
#define NQC  (NQ * NC)   // 81900
#define Q4   (NQC / 4)   // 20475
#define HHALF 10238      // ceil(Q4/2)
#define PRE  10000
#define POST 100
#define TBITS 13
#define TBINS (1 << TBITS)   // 8192
#define TSHIFT (32 - TBITS)  // 19
#define K_WIN 64
#define HSEG 1024
#define KS   2780        // sampled (1/4) suffix-count target (verified rounds 3-9)
#define CAPH 7680        // per-half key capacity (~5.6K expected, >19 sigma margin)
#define NSLOT 15         // ceil(2*CAPH / 1024)

typedef unsigned long long ull;

// ---- workspace ----
#define WS_CNT 0                     // 256 * 4 B
#define WS_GH  4096                  // 256 * 8192 * 2B = 4 MB per-half exact hist
#define WS_KEYS (4096 + 4*1024*1024) // 128 * 2 * 7680 * 8 = 15.73 MB

__device__ __forceinline__ uint32_t fkey(float f) {
    uint32_t b = __float_as_uint(f);
    return (b & 0x80000000u) ? ~b : (b | 0x80000000u);
}
__device__ __forceinline__ float unkey(uint32_t u) {
    uint32_t b = (u & 0x80000000u) ? (u & 0x7FFFFFFFu) : ~u;
    return __uint_as_float(b);
}
__device__ __forceinline__ uint32_t qclamp(uint32_t q) { return (q < NQ) ? q : (NQ - 1); }

__device__ __forceinline__ ull shflx(ull v, int j) {
    uint32_t lo = (uint32_t)__shfl_xor((int)(uint32_t)v, j, 64);
    uint32_t hi = (uint32_t)__shfl_xor((int)(uint32_t)(v >> 32), j, 64);
    return ((ull)hi << 32) | (ull)lo;
}
__device__ __forceinline__ ull cex(ull v, int j, bool lower, bool desc) {
    ull pb = shflx(v, j);
    ull a = lower ? v : pb;
    ull b = lower ? pb : v;
    bool sw = desc ? (a < b) : (a > b);
    return sw ? pb : v;
}
__device__ __forceinline__ void ce(ull& a, ull& b, bool desc) {
    bool sw = desc ? (a < b) : (a > b);
    if (sw) { ull t = a; a = b; b = t; }
}

// ============ Kernel 1 (256 blocks, 2/image): Tlo + compact keys + exact half hist ============
__global__ void __launch_bounds__(1024) k_compact(const float* __restrict__ logits,
                                                  ull* __restrict__ keys,
                                                  uint16_t* __restrict__ ghist,
                                                  uint32_t* __restrict__ cnts) {
    const int img = blockIdx.x >> 1;
    const int h = blockIdx.x & 1;
    const int tid = threadIdx.x;
    const int lane = tid & 63;
    __shared__ uint32_t hist[TBINS];   // 32 KB (sampled, then reused for exact)
    __shared__ uint32_t part[1024];
    __shared__ uint32_t sTB, sCnt;
    const float4* lg4 = (const float4*)(logits + (size_t)img * NQC);
    for (int i = tid; i < TBINS; i += 1024) hist[i] = 0u;
    if (tid == 0) sCnt = 0u;
    float4 sv[5];
    #pragma unroll
    for (int c = 0; c < 5; ++c) sv[c] = lg4[c * 4096 + tid];   // max 17407 < 20475
    __syncthreads();
    #pragma unroll
    for (int c = 0; c < 5; ++c) {
        atomicAdd(&hist[fkey(sv[c].x) >> TSHIFT], 1u);
        atomicAdd(&hist[fkey(sv[c].y) >> TSHIFT], 1u);
        atomicAdd(&hist[fkey(sv[c].z) >> TSHIFT], 1u);
        atomicAdd(&hist[fkey(sv[c].w) >> TSHIFT], 1u);
    }
    __syncthreads();
    {
        uint32_t s = 0;
        int b0 = tid * 8;
        #pragma unroll
        for (int j = 0; j < 8; ++j) s += hist[b0 + j];
        part[tid] = s;
    }
    __syncthreads();
    if (tid < 64) {   // wave-0 suffix scan -> Tlo BIN (verified rounds 3-9)
        uint32_t pv[16]; uint32_t tot = 0;
        #pragma unroll
        for (int j = 0; j < 16; ++j) { pv[j] = part[tid * 16 + j]; tot += pv[j]; }
        uint32_t sinc = tot;
        #pragma unroll
        for (int off = 1; off < 64; off <<= 1) {
            uint32_t o = (uint32_t)__shfl_down((int)sinc, off, 64);
            if (tid + off < 64) sinc += o;
        }
        uint32_t cum = sinc - tot;
        for (int j = 15; j >= 0; --j) {
            if (cum < KS && cum + pv[j] >= KS) {
                int pbn = (tid * 16 + j) * 8;
                uint32_t c2 = cum;
                for (int b = pbn + 7; b >= pbn; --b) {
                    if (c2 + hist[b] >= KS) { sTB = (uint32_t)b; break; }
                    c2 += hist[b];
                }
            }
            cum += pv[j];
        }
    }
    __syncthreads();
    const uint32_t TB = sTB;
    // reset hist for exact candidate histogram (only stored keys counted)
    for (int i = tid; i < TBINS; i += 1024) hist[i] = 0u;
    __syncthreads();
    // compact own half's candidates to global segment (order irrelevant)
    ull* seg = keys + (size_t)(img * 2 + h) * CAPH;
    const int lo = h * HHALF;
    const int hi = (lo + HHALF < Q4) ? (lo + HHALF) : Q4;
    for (int i0 = lo; i0 < hi; i0 += 1024) {
        int i = i0 + tid;
        bool inb = (i < hi);
        float4 v = inb ? lg4[i] : make_float4(0.f, 0.f, 0.f, 0.f);
        float comp[4] = {v.x, v.y, v.z, v.w};
        #pragma unroll
        for (int c = 0; c < 4; ++c) {
            uint32_t u = fkey(comp[c]);
            bool pass = inb && ((u >> TSHIFT) >= TB);
            ull m = __ballot(pass);
            if (m) {
                uint32_t wb = 0u;
                if (lane == 0) wb = atomicAdd(&sCnt, (uint32_t)__popcll(m));
                wb = (uint32_t)__shfl((int)wb, 0, 64);
                if (pass) {
                    uint32_t p = wb + (uint32_t)__popcll(m & ((1ull << lane) - 1ull));
                    uint32_t fi = (uint32_t)(i * 4 + c);
                    if (p < CAPH) {
                        seg[p] = ((ull)u << 32) | (ull)(0xFFFFFFFFu - fi);
                        atomicAdd(&hist[u >> TSHIFT], 1u);
                    }
                }
            }
        }
    }
    __syncthreads();
    uint16_t* g = ghist + (size_t)(img * 2 + h) * TBINS;   // bin count <= 40950 < 65536
    for (int i = tid; i < TBINS; i += 1024) g[i] = (uint16_t)hist[i];
    if (tid == 0) cnts[img * 2 + h] = (sCnt < CAPH) ? sCnt : CAPH;
}

// ============ Kernel 2 (128 blocks, 1/image): scan + classify + sorts + 64-wide NMS ============
__global__ void __launch_bounds__(1024) k_sel(const ull* __restrict__ keys,
                                              const uint16_t* __restrict__ ghist,
                                              const uint32_t* __restrict__ cnts,
                                              const float* __restrict__ pred_boxes,
                                              const float* __restrict__ target_sizes,
                                              float* __restrict__ out) {
    const int img = blockIdx.x;
    const int tid = threadIdx.x;
    const int lane = tid & 63;
    const int wv = tid >> 6;                 // 16 waves

    __shared__ uint32_t hist[TBINS];         // 32 KB (live through continuations)
    __shared__ uint32_t part[1024];          // 4 KB
    __shared__ float4 shPB[NQ];              // 14.4 KB
    __shared__ ull binK[HSEG];               // 8 KB
    __shared__ ull headK[HSEG];              // 8 KB
    __shared__ float aX1[POST], aY1[POST], aX2[POST], aY2[POST], aAr[POST];
    __shared__ int   aCl[POST];
    __shared__ float s_x1[K_WIN], s_y1[K_WIN], s_x2[K_WIN], s_y2[K_WIN];
    __shared__ int   s_cl[K_WIN];
    __shared__ ull   s_em[K_WIN];
    __shared__ ull sF0;
    __shared__ uint32_t sCntA, sCntB, sMX;
    __shared__ uint32_t sB1, sTp1, sB2, sTp2, sTK;

    const float ih = target_sizes[img * 2 + 0];
    const float iw = target_sizes[img * 2 + 1];
    const float* pb = pred_boxes + (size_t)img * NQ * 4;

    auto mckey = [&](uint32_t f) -> uint32_t {   // identical arithmetic rounds 0-9
        uint32_t q = qclamp(f / NC);
        float4 bb = shPB[q];
        float x1 = (bb.x - 0.5f * bb.z) * iw;
        float y1 = (bb.y - 0.5f * bb.w) * ih;
        float x2 = (bb.x + 0.5f * bb.z) * iw;
        float y2 = (bb.y + 0.5f * bb.w) * ih;
        return fkey(fmaxf(fmaxf(x1, y1), fmaxf(x2, y2)));
    };

    // ---- P0: shPB, hist = g0+g1 (plain stores) + part, key regs, zero state ----
    if (tid < NQ) shPB[tid] = ((const float4*)pb)[tid];
    binK[tid] = 0ull; headK[tid] = 0ull;
    if (tid == 0) { sCntA = 0u; sCntB = 0u; sMX = 0u; sF0 = 0ull;
                    sB1 = 0u; sTp1 = 1u; sB2 = 0u; sTp2 = 0u; sTK = 0u; }
    {
        const uint16_t* g0 = ghist + (size_t)(img * 2) * TBINS;
        const uint16_t* g1 = g0 + TBINS;
        uint32_t s = 0;
        int b0 = tid * 8;
        #pragma unroll
        for (int j = 0; j < 8; ++j) {
            uint32_t hv = (uint32_t)g0[b0 + j] + (uint32_t)g1[b0 + j];
            hist[b0 + j] = hv;
            s += hv;
        }
        part[tid] = s;
    }
    const uint32_t c0 = cnts[img * 2 + 0];
    const uint32_t c1 = cnts[img * 2 + 1];
    const int total = (int)(c0 + c1);
    const ull* seg0 = keys + (size_t)(img * 2) * CAPH;
    const ull* seg1 = seg0 + CAPH;
    ull kk[NSLOT];
    #pragma unroll
    for (int j = 0; j < NSLOT; ++j) {
        int i = tid + (j << 10);
        ull x = 0ull;
        if (i < total) x = (i < (int)c0) ? seg0[i] : seg1[i - (int)c0];
        kk[j] = x;
    }
    __syncthreads();

    // ---- P1: dual-target scan (B1@TK, B2@T2) ----
    if (tid < 64) {
        uint32_t pv[16]; uint32_t tot = 0;
        #pragma unroll
        for (int j = 0; j < 16; ++j) { pv[j] = part[tid * 16 + j]; tot += pv[j]; }
        uint32_t sinc = tot;
        #pragma unroll
        for (int off = 1; off < 64; off <<= 1) {
            uint32_t o = (uint32_t)__shfl_down((int)sinc, off, 64);
            if (tid + off < 64) sinc += o;
        }
        uint32_t tt = (uint32_t)__shfl((int)sinc, 0, 64);
        uint32_t TKl = (tt < PRE) ? tt : PRE;
        uint32_t T2l = (TKl < HSEG) ? TKl : HSEG;
        if (tid == 0) sTK = TKl;
        uint32_t cum = sinc - tot;
        for (int j = 15; j >= 0; --j) {
            if (cum < TKl && cum + pv[j] >= TKl) {
                int pbn = (tid * 16 + j) * 8;
                uint32_t c2 = cum;
                for (int b = pbn + 7; b >= pbn; --b) {
                    if (c2 + hist[b] >= TKl) { sB1 = (uint32_t)b; sTp1 = TKl - c2; break; }
                    c2 += hist[b];
                }
            }
            if (cum < T2l && cum + pv[j] >= T2l) {
                int pbn = (tid * 16 + j) * 8;
                uint32_t c2 = cum;
                for (int b = pbn + 7; b >= pbn; --b) {
                    if (c2 + hist[b] >= T2l) { sB2 = (uint32_t)b; sTp2 = T2l - c2; break; }
                    c2 += hist[b];
                }
            }
            cum += pv[j];
        }
    }
    __syncthreads();
    const uint32_t B1 = sB1, tp1 = sTp1, B2 = sB2;
    const uint32_t TK = sTK;
    const int C1 = (int)(((TK < (uint32_t)HSEG) ? TK : (uint32_t)HSEG) - sTp2);

    // ---- P2: classify registers: offD part (bin>B1) + binK (==B1) + headK (>B2) ----
    uint32_t lmx = 0u;
    #pragma unroll
    for (int j = 0; j < NSLOT; ++j) {
        ull x = kk[j];
        uint32_t bin = (uint32_t)(x >> 51);
        bool liveK = (x != 0ull);
        if (liveK && bin > B1) { uint32_t km = mckey(~(uint32_t)x); if (km > lmx) lmx = km; }
        bool isA = liveK && (bin == B1);
        bool isB = liveK && (bin > B2);
        ull mA = __ballot(isA);
        if (mA) {
            uint32_t wb = 0u;
            if (lane == 0) wb = atomicAdd(&sCntA, (uint32_t)__popcll(mA));
            wb = (uint32_t)__shfl((int)wb, 0, 64);
            if (isA) {
                uint32_t p = wb + (uint32_t)__popcll(mA & ((1ull << lane) - 1ull));
                if (p < HSEG) binK[p] = x;
            }
        }
        ull mB = __ballot(isB);
        if (mB) {
            uint32_t wb = 0u;
            if (lane == 0) wb = atomicAdd(&sCntB, (uint32_t)__popcll(mB));
            wb = (uint32_t)__shfl((int)wb, 0, 64);
            if (isB) {
                uint32_t p = wb + (uint32_t)__popcll(mB & ((1ull << lane) - 1ull));
                if (p < HSEG) headK[p] = x;
            }
        }
    }
    __syncthreads();

    // ---- P3: DUAL sort (binK: waves 0-3, headK: waves 4-7), desc (verified r7-r9) ----
    {
        ull r0 = 0, r1 = 0, r2 = 0, r3 = 0;
        const int cw = wv & 3;
        const int cb = cw << 8;
        ull* A = (wv < 4) ? binK : headK;
        if (wv < 8) {
            r0 = A[cb | lane]; r1 = A[cb | 64 | lane];
            r2 = A[cb | 128 | lane]; r3 = A[cb | 192 | lane];
            #pragma unroll
            for (int k2 = 2; k2 <= 32; k2 <<= 1) {
                bool d = ((lane & k2) == 0);
                #pragma unroll
                for (int j = 16; j >= 1; j >>= 1) {
                    if (j <= (k2 >> 1)) {
                        bool lw = ((lane & j) == 0);
                        r0 = cex(r0, j, lw, d); r1 = cex(r1, j, lw, d);
                        r2 = cex(r2, j, lw, d); r3 = cex(r3, j, lw, d);
                    }
                }
            }
            #pragma unroll
            for (int j = 32; j >= 1; j >>= 1) {          // k=64
                bool lw = ((lane & j) == 0);
                r0 = cex(r0, j, lw, true);  r1 = cex(r1, j, lw, false);
                r2 = cex(r2, j, lw, true);  r3 = cex(r3, j, lw, false);
            }
            ce(r0, r1, true); ce(r2, r3, false);         // k=128
            #pragma unroll
            for (int j = 32; j >= 1; j >>= 1) {
                bool lw = ((lane & j) == 0);
                r0 = cex(r0, j, lw, true);  r1 = cex(r1, j, lw, true);
                r2 = cex(r2, j, lw, false); r3 = cex(r3, j, lw, false);
            }
            {                                            // k=256
                bool d = ((cw & 1) == 0);
                ce(r0, r2, d); ce(r1, r3, d); ce(r0, r1, d); ce(r2, r3, d);
                #pragma unroll
                for (int j = 32; j >= 1; j >>= 1) {
                    bool lw = ((lane & j) == 0);
                    r0 = cex(r0, j, lw, d); r1 = cex(r1, j, lw, d);
                    r2 = cex(r2, j, lw, d); r3 = cex(r3, j, lw, d);
                }
            }
            A[cb | lane] = r0; A[cb | 64 | lane] = r1;
            A[cb | 128 | lane] = r2; A[cb | 192 | lane] = r3;
        }
        __syncthreads();
        {   // k=512, j=256 cross-chunk
            ull* Bp = (tid >> 9) ? headK : binK;
            int t = tid & 511;
            int i = ((t & ~255) << 1) | (t & 255);
            int ixj = i | 256;
            bool d = ((i & 512) == 0);
            ull a = Bp[i], b = Bp[ixj];
            bool sw = d ? (a < b) : (a > b);
            if (sw) { Bp[i] = b; Bp[ixj] = a; }
        }
        __syncthreads();
        if (wv < 8) {
            r0 = A[cb | lane]; r1 = A[cb | 64 | lane];
            r2 = A[cb | 128 | lane]; r3 = A[cb | 192 | lane];
            bool d = ((cw & 2) == 0);
            ce(r0, r2, d); ce(r1, r3, d); ce(r0, r1, d); ce(r2, r3, d);
            #pragma unroll
            for (int j = 32; j >= 1; j >>= 1) {
                bool lw = ((lane & j) == 0);
                r0 = cex(r0, j, lw, d); r1 = cex(r1, j, lw, d);
                r2 = cex(r2, j, lw, d); r3 = cex(r3, j, lw, d);
            }
            A[cb | lane] = r0; A[cb | 64 | lane] = r1;
            A[cb | 128 | lane] = r2; A[cb | 192 | lane] = r3;
        }
        __syncthreads();
        {   // k=1024, j=512
            ull* Bp = (tid >> 9) ? headK : binK;
            int t = tid & 511;
            ull a = Bp[t], b = Bp[t | 512];
            if (a < b) { Bp[t] = b; Bp[t | 512] = a; }
        }
        __syncthreads();
        {   // k=1024, j=256
            ull* Bp = (tid >> 9) ? headK : binK;
            int t = tid & 511;
            int i = ((t & ~255) << 1) | (t & 255);
            int ixj = i | 256;
            ull a = Bp[i], b = Bp[ixj];
            if (a < b) { Bp[i] = b; Bp[ixj] = a; }
        }
        __syncthreads();
        if (wv < 8) {
            r0 = A[cb | lane]; r1 = A[cb | 64 | lane];
            r2 = A[cb | 128 | lane]; r3 = A[cb | 192 | lane];
            ce(r0, r2, true); ce(r1, r3, true); ce(r0, r1, true); ce(r2, r3, true);
            #pragma unroll
            for (int j = 32; j >= 1; j >>= 1) {
                bool lw = ((lane & j) == 0);
                r0 = cex(r0, j, lw, true); r1 = cex(r1, j, lw, true);
                r2 = cex(r2, j, lw, true); r3 = cex(r3, j, lw, true);
            }
            A[cb | lane] = r0; A[cb | 64 | lane] = r1;
            A[cb | 128 | lane] = r2; A[cb | 192 | lane] = r3;
        }
        __syncthreads();
    }

    // ---- P4: offD = max(sweep lmx, top-tp1 prefix of sorted binK); sF0 ----
    if (tid < (int)tp1) {
        ull x = binK[tid];
        if (x != 0ull) { uint32_t km = mckey(~(uint32_t)x); if (km > lmx) lmx = km; }
    }
    for (int off = 32; off > 0; off >>= 1) {
        uint32_t o = (uint32_t)__shfl_down((int)lmx, off, 64);
        if (o > lmx) lmx = o;
    }
    if (lane == 0) atomicMax(&sMX, lmx);
    if (tid == 0 && C1 > 0) sF0 = headK[0];
    __syncthreads();
    float offD;
    {
        uint32_t m = sMX;
        uint32_t b = (m & 0x80000000u) ? (m & 0x7FFFFFFFu) : ~m;
        offD = __uint_as_float(b) + 1.0f;    // max_coord + 1
    }

    // single-array sort1024 for rare continuation segments (verified r6-r9)
    auto sort1024 = [&]() {
        const int idx = tid;
        ull x = headK[idx];
        #pragma unroll
        for (int k2 = 2; k2 <= 32; k2 <<= 1) {
            bool d = ((lane & k2) == 0);
            #pragma unroll
            for (int j = 16; j >= 1; j >>= 1)
                if (j <= (k2 >> 1)) x = cex(x, j, (lane & j) == 0, d);
        }
        {
            bool d = ((idx & 64) == 0);
            #pragma unroll
            for (int j = 32; j >= 1; j >>= 1) x = cex(x, j, (lane & j) == 0, d);
        }
        for (int k = 128; k <= 1024; k <<= 1) {
            headK[idx] = x;
            __syncthreads();
            for (int j = k >> 1; j >= 64; j >>= 1) {
                if (tid < 512) {
                    int i2 = ((tid & ~(j - 1)) << 1) | (tid & (j - 1));
                    int ixj = i2 | j;
                    ull a = headK[i2], b = headK[ixj];
                    bool sw = ((i2 & k) == 0) ? (a < b) : (a > b);
                    if (sw) { headK[i2] = b; headK[ixj] = a; }
                }
                __syncthreads();
            }
            x = headK[idx];
            bool d = ((idx & k) == 0);
            #pragma unroll
            for (int j = 32; j >= 1; j >>= 1) x = cex(x, j, (lane & j) == 0, d);
        }
        headK[idx] = x;
        __syncthreads();
    };

    // ---- P5: 64-wide lazy windowed greedy NMS (wave wv owns candidates 4wv..4wv+3) ----
    int npick = 0, base = 0, segbase = 0, segend = C1;
    int bcur = (int)B2;
    bool needF0 = (C1 == 0);
    while (npick < POST) {
        if (base >= segend) {
            if (segend >= (int)TK) {   // ranks exhausted: reference repeats index 0
                ull x0 = sF0;
                uint32_t f0 = ~(uint32_t)x0;
                uint32_t u0 = (uint32_t)(x0 >> 32);
                uint32_t q0 = qclamp(f0 / NC);
                uint32_t cc0 = f0 - (f0 / NC) * NC;
                float4 bb = shPB[q0];
                float rx1 = (bb.x - 0.5f * bb.z) * iw;
                float ry1 = (bb.y - 0.5f * bb.w) * ih;
                float rx2 = (bb.x + 0.5f * bb.z) * iw;
                float ry2 = (bb.y + 0.5f * bb.w) * ih;
                float sc = 1.0f / (1.0f + expf(-unkey(u0)));
                for (int p2 = npick + tid; p2 < POST; p2 += 1024) {
                    out[img * POST + p2] = sc;
                    out[BS * POST + img * POST + p2] = (float)cc0;
                    float* ob2 = out + 2 * BS * POST + ((size_t)img * POST + p2) * 4;
                    ob2[0] = rx1; ob2[1] = ry1; ob2[2] = rx2; ob2[3] = ry2;
                }
                break;
            }
            // continuation: next nonempty bin, gather from compacted keys + sort
            while (bcur > 0 && hist[bcur] == 0u) --bcur;
            headK[tid] = 0ull;
            if (tid == 0) sCntA = 0u;
            __syncthreads();
            for (int i0 = 0; i0 < total; i0 += 1024) {
                int i = i0 + tid;
                ull x = 0ull;
                if (i < total) x = (i < (int)c0) ? seg0[i] : seg1[i - (int)c0];
                bool pass = (x != 0ull) && ((uint32_t)(x >> 51) == (uint32_t)bcur);
                ull m = __ballot(pass);
                if (m) {
                    uint32_t wb = 0u;
                    if (lane == 0) wb = atomicAdd(&sCntA, (uint32_t)__popcll(m));
                    wb = (uint32_t)__shfl((int)wb, 0, 64);
                    if (pass) {
                        uint32_t p = wb + (uint32_t)__popcll(m & ((1ull << lane) - 1ull));
                        if (p < HSEG) headK[p] = x;
                    }
                }
            }
            __syncthreads();
            sort1024();
            int avail = (int)((sCntA < (uint32_t)HSEG) ? sCntA : (uint32_t)HSEG);
            int take = (int)TK - segend; if (take > avail) take = avail;
            if (needF0) { if (tid == 0) sF0 = headK[0]; needF0 = false; __syncthreads(); }
            segbase = segend; segend += take; --bcur;
            continue;
        }

        // stage A: wave wv computes its 4 candidates (all wave-uniform)
        bool valv[4]; uint32_t ccv[4], ukv[4];
        float X1[4], Y1[4], X2[4], Y2[4];
        #pragma unroll
        for (int off = 0; off < 4; ++off) {
            const int ci = 4 * wv + off;
            const int r = base + ci;
            valv[off] = (r < segend);
            const ull xk = headK[valv[off] ? (r - segbase) : 0];
            const uint32_t f = valv[off] ? ~(uint32_t)xk : 0u;
            ukv[off] = (uint32_t)(xk >> 32);
            const uint32_t q = qclamp(f / NC);
            ccv[off] = f - (f / NC) * NC;
            float4 bb = shPB[q];
            X1[off] = (bb.x - 0.5f * bb.z) * iw;
            Y1[off] = (bb.y - 0.5f * bb.w) * ih;
            X2[off] = (bb.x + 0.5f * bb.z) * iw;
            Y2[off] = (bb.y + 0.5f * bb.w) * ih;
        }
        if (lane == 0) {
            #pragma unroll
            for (int off = 0; off < 4; ++off) {
                const int ci = 4 * wv + off;
                s_x1[ci] = X1[off]; s_y1[ci] = Y1[off];
                s_x2[ci] = X2[off]; s_y2[ci] = Y2[off];
                s_cl[ci] = valv[off] ? (int)ccv[off] : -1;
            }
        }
        __syncthreads();

        // stage B: conflicts per candidate (lane = prior in-window candidate index)
        float ov[4], CX1[4], CY1[4], CX2[4], CY2[4], CAR[4];
        ull emv[4];
        #pragma unroll
        for (int off = 0; off < 4; ++off) {
            const int ci = 4 * wv + off;
            const float o = (float)ccv[off] * offD;
            ov[off] = o;
            CX1[off] = X1[off] + o; CY1[off] = Y1[off] + o;
            CX2[off] = X2[off] + o; CY2[off] = Y2[off] + o;
            CAR[off] = (CX2[off] - CX1[off]) * (CY2[off] - CY1[off]);
            bool cf = false;
            if (valv[off] && lane < ci && s_cl[lane] == (int)ccv[off]) {
                float jx1 = s_x1[lane] + o, jy1 = s_y1[lane] + o;
                float jx2 = s_x2[lane] + o, jy2 = s_y2[lane] + o;
                float arj = (jx2 - jx1) * (jy2 - jy1);
                float xx1 = fmaxf(jx1, CX1[off]), yy1 = fmaxf(jy1, CY1[off]);
                float xx2 = fminf(jx2, CX2[off]), yy2 = fminf(jy2, CY2[off]);
                float inter = fmaxf(xx2 - xx1, 0.0f) * fmaxf(yy2 - yy1, 0.0f);
                float uni = (arj + CAR[off]) - inter;
                float iou = inter / fmaxf(uni, 1e-9f);
                cf = !(iou <= 0.7f);
            }
            emv[off] = __ballot(cf) & ((ci == 0) ? 0ull : ((ci >= 64) ? ~0ull : ((1ull << ci) - 1ull)));
        }
        // fused prior-picks scan (one pass over accepted list for all 4 candidates)
        bool pf[4] = {false, false, false, false};
        for (int i2 = lane; i2 < npick; i2 += 64) {
            const int acl = aCl[i2];
            const float ax1 = aX1[i2], ay1 = aY1[i2], ax2 = aX2[i2], ay2 = aY2[i2];
            const float aar = aAr[i2];
            #pragma unroll
            for (int off = 0; off < 4; ++off) {
                if (valv[off] && acl == (int)ccv[off]) {
                    float jx1 = ax1 + ov[off], jy1 = ay1 + ov[off];
                    float jx2 = ax2 + ov[off], jy2 = ay2 + ov[off];
                    float xx1 = fmaxf(jx1, CX1[off]), yy1 = fmaxf(jy1, CY1[off]);
                    float xx2 = fminf(jx2, CX2[off]), yy2 = fminf(jy2, CY2[off]);
                    float inter = fmaxf(xx2 - xx1, 0.0f) * fmaxf(yy2 - yy1, 0.0f);
                    float uni = (aar + CAR[off]) - inter;
                    float iou = inter / fmaxf(uni, 1e-9f);
                    pf[off] |= !(iou <= 0.7f);
                }
            }
        }
        #pragma unroll
        for (int off = 0; off < 4; ++off) {
            bool anyP = (__ballot(pf[off]) != 0ull);
            if (lane == 0) {
                const int ci = 4 * wv + off;
                s_em[ci] = emv[off] | ((anyP || !valv[off]) ? (1ull << 63) : 0ull);
            }
        }
        __syncthreads();

        // stage C: uniform sequential resolution over 64 candidates
        ull acc = 0ull; int a = 0;
        const int room = POST - npick;
        #pragma unroll
        for (int ci = 0; ci < K_WIN; ++ci) {
            ull ew = s_em[ci];
            if (!(ew >> 63) && a < room && ((ew & acc) == 0ull)) {
                acc |= (1ull << ci); ++a;
            }
        }

        // stage D: lanes 0-3 of each wave write their accepted candidates
        #pragma unroll
        for (int off = 0; off < 4; ++off) {
            const int ci = 4 * wv + off;
            if (((acc >> ci) & 1ull) && lane == off) {
                int p = npick + (int)__popcll(acc & ((1ull << ci) - 1ull));
                float sc = 1.0f / (1.0f + expf(-unkey(ukv[off])));
                out[img * POST + p] = sc;
                out[BS * POST + img * POST + p] = (float)ccv[off];
                float* ob2 = out + 2 * BS * POST + ((size_t)img * POST + p) * 4;
                ob2[0] = X1[off]; ob2[1] = Y1[off]; ob2[2] = X2[off]; ob2[3] = Y2[off];
                aX1[p] = X1[off]; aY1[p] = Y1[off]; aX2[p] = X2[off]; aY2[p] = Y2[off];
                aAr[p] = CAR[off]; aCl[p] = (int)ccv[off];
            }
        }
        npick += a;
        base += K_WIN;
        // next iteration's stage-A barrier orders stage-D writes before stage-B reads
    }
}

extern "C" void kernel_launch(void* const* d_in, const int* in_sizes, int n_in,
                              void* d_out, int out_size, void* d_ws, size_t ws_size,
                              hipStream_t stream) {
    const float* logits = (const float*)d_in[0];
    const float* boxes  = (const float*)d_in[1];
    const float* tsizes = (const float*)d_in[2];
    float* out = (float*)d_out;

    uint32_t* cnts = (uint32_t*)((char*)d_ws + WS_CNT);
    uint16_t* ghist = (uint16_t*)((char*)d_ws + WS_GH);
    ull* keys = (ull*)((char*)d_ws + WS_KEYS);

    k_compact<<<2 * BS, 1024, 0, stream>>>(logits, keys, ghist, cnts);
    k_sel<<<BS, 1024, 0, stream>>>(keys, ghist, cnts, boxes, tsizes, out);
}

// Round 11
// 138.232 us; speedup vs baseline: 1.0629x; 1.0629x over previous
//
#include <hip/hip_runtime.h>
#include <cstdint>

#pragma clang fp contract(off)

#define BS   128
#define NQ   900
#define NC   91
#define NQC  (NQ * NC)   // 81900
#define Q4   (NQC / 4)   // 20475
#define HHALF 10238      // ceil(Q4/2)
#define PRE  10000
#define POST 100
#define TBITS 13
#define TBINS (1 << TBITS)   // 8192
#define TSHIFT (32 - TBITS)  // 19
#define K_WIN 16
#define HSEG 1024
#define KS   2780        // sampled (1/4) suffix-count target (verified rounds 3-10)
#define CAPH 7680        // per-half key capacity (~5.6K expected, >19 sigma margin)
#define NSLOT 15         // ceil(2*CAPH / 1024)

typedef unsigned long long ull;

// ---- workspace ----
#define WS_CNT 0                     // 256 * 4 B
#define WS_GH  4096                  // 256 * 8192 * 2B = 4 MB per-half exact hist
#define WS_KEYS (4096 + 4*1024*1024) // 128 * 2 * 7680 * 8 = 15.73 MB

__device__ __forceinline__ uint32_t fkey(float f) {
    uint32_t b = __float_as_uint(f);
    return (b & 0x80000000u) ? ~b : (b | 0x80000000u);
}
__device__ __forceinline__ float unkey(uint32_t u) {
    uint32_t b = (u & 0x80000000u) ? (u & 0x7FFFFFFFu) : ~u;
    return __uint_as_float(b);
}
__device__ __forceinline__ uint32_t qclamp(uint32_t q) { return (q < NQ) ? q : (NQ - 1); }

__device__ __forceinline__ ull shflx(ull v, int j) {
    uint32_t lo = (uint32_t)__shfl_xor((int)(uint32_t)v, j, 64);
    uint32_t hi = (uint32_t)__shfl_xor((int)(uint32_t)(v >> 32), j, 64);
    return ((ull)hi << 32) | (ull)lo;
}
__device__ __forceinline__ ull cex(ull v, int j, bool lower, bool desc) {
    ull pb = shflx(v, j);
    ull a = lower ? v : pb;
    ull b = lower ? pb : v;
    bool sw = desc ? (a < b) : (a > b);
    return sw ? pb : v;
}
__device__ __forceinline__ void ce(ull& a, ull& b, bool desc) {
    bool sw = desc ? (a < b) : (a > b);
    if (sw) { ull t = a; a = b; b = t; }
}

// ============ Kernel 1 (256 blocks, 2/image): Tlo + compact keys + exact half hist ============
// Compact loop: ONE atomic chain per 2048 elements (8 ballots, accumulated popcounts),
// 2-deep float4 load unroll. Key SET identical to rounds 9/10 (same predicate);
// intra-segment order differs but all consumers sort (unique keys) -> bit-identical output.
__global__ void __launch_bounds__(1024) k_compact(const float* __restrict__ logits,
                                                  ull* __restrict__ keys,
                                                  uint16_t* __restrict__ ghist,
                                                  uint32_t* __restrict__ cnts) {
    const int img = blockIdx.x >> 1;
    const int h = blockIdx.x & 1;
    const int tid = threadIdx.x;
    const int lane = tid & 63;
    __shared__ uint32_t hist[TBINS];   // 32 KB (sampled, then reused for exact)
    __shared__ uint32_t part[1024];
    __shared__ uint32_t sTB, sCnt;
    const float4* lg4 = (const float4*)(logits + (size_t)img * NQC);
    for (int i = tid; i < TBINS; i += 1024) hist[i] = 0u;
    if (tid == 0) sCnt = 0u;
    float4 sv[5];
    #pragma unroll
    for (int c = 0; c < 5; ++c) sv[c] = lg4[c * 4096 + tid];   // max 17407 < 20475
    __syncthreads();
    #pragma unroll
    for (int c = 0; c < 5; ++c) {
        atomicAdd(&hist[fkey(sv[c].x) >> TSHIFT], 1u);
        atomicAdd(&hist[fkey(sv[c].y) >> TSHIFT], 1u);
        atomicAdd(&hist[fkey(sv[c].z) >> TSHIFT], 1u);
        atomicAdd(&hist[fkey(sv[c].w) >> TSHIFT], 1u);
    }
    __syncthreads();
    {
        uint32_t s = 0;
        int b0 = tid * 8;
        #pragma unroll
        for (int j = 0; j < 8; ++j) s += hist[b0 + j];
        part[tid] = s;
    }
    __syncthreads();
    if (tid < 64) {   // wave-0 suffix scan -> Tlo BIN (verified rounds 3-10)
        uint32_t pv[16]; uint32_t tot = 0;
        #pragma unroll
        for (int j = 0; j < 16; ++j) { pv[j] = part[tid * 16 + j]; tot += pv[j]; }
        uint32_t sinc = tot;
        #pragma unroll
        for (int off = 1; off < 64; off <<= 1) {
            uint32_t o = (uint32_t)__shfl_down((int)sinc, off, 64);
            if (tid + off < 64) sinc += o;
        }
        uint32_t cum = sinc - tot;
        for (int j = 15; j >= 0; --j) {
            if (cum < KS && cum + pv[j] >= KS) {
                int pbn = (tid * 16 + j) * 8;
                uint32_t c2 = cum;
                for (int b = pbn + 7; b >= pbn; --b) {
                    if (c2 + hist[b] >= KS) { sTB = (uint32_t)b; break; }
                    c2 += hist[b];
                }
            }
            cum += pv[j];
        }
    }
    __syncthreads();
    const uint32_t TB = sTB;
    // reset hist for exact candidate histogram (only stored keys counted)
    for (int i = tid; i < TBINS; i += 1024) hist[i] = 0u;
    __syncthreads();
    // compact own half's candidates to global segment (order irrelevant)
    ull* seg = keys + (size_t)(img * 2 + h) * CAPH;
    const int lo = h * HHALF;
    const int hi = (lo + HHALF < Q4) ? (lo + HHALF) : Q4;
    for (int i0 = lo; i0 < hi; i0 += 2048) {
        float4 v[2]; bool inb[2]; int ii[2];
        #pragma unroll
        for (int s = 0; s < 2; ++s) {
            int i = i0 + (s << 10) + tid;
            ii[s] = i; inb[s] = (i < hi);
            v[s] = inb[s] ? lg4[i] : make_float4(0.f, 0.f, 0.f, 0.f);
        }
        uint32_t u[8]; bool pass[8];
        #pragma unroll
        for (int s = 0; s < 2; ++s) {
            u[s * 4 + 0] = fkey(v[s].x); u[s * 4 + 1] = fkey(v[s].y);
            u[s * 4 + 2] = fkey(v[s].z); u[s * 4 + 3] = fkey(v[s].w);
            #pragma unroll
            for (int c = 0; c < 4; ++c)
                pass[s * 4 + c] = inb[s] && ((u[s * 4 + c] >> TSHIFT) >= TB);
        }
        ull m[8]; uint32_t pc[8]; uint32_t tot = 0;
        #pragma unroll
        for (int c = 0; c < 8; ++c) {
            m[c] = __ballot(pass[c]);
            pc[c] = (uint32_t)__popcll(m[c]);
            tot += pc[c];
        }
        uint32_t wb = 0u;
        if (lane == 0 && tot) wb = atomicAdd(&sCnt, tot);
        wb = (uint32_t)__shfl((int)wb, 0, 64);
        ull lm = (1ull << lane) - 1ull;
        uint32_t off = 0;
        #pragma unroll
        for (int c = 0; c < 8; ++c) {
            if (pass[c]) {
                uint32_t p = wb + off + (uint32_t)__popcll(m[c] & lm);
                uint32_t fi = (uint32_t)(ii[c >> 2] * 4 + (c & 3));
                if (p < CAPH) {
                    seg[p] = ((ull)u[c] << 32) | (ull)(0xFFFFFFFFu - fi);
                    atomicAdd(&hist[u[c] >> TSHIFT], 1u);
                }
            }
            off += pc[c];
        }
    }
    __syncthreads();
    uint16_t* g = ghist + (size_t)(img * 2 + h) * TBINS;   // bin count <= 40950 < 65536
    for (int i = tid; i < TBINS; i += 1024) g[i] = (uint16_t)hist[i];
    if (tid == 0) cnts[img * 2 + h] = (sCnt < CAPH) ? sCnt : CAPH;
}

// ============ Kernel 2 (128 blocks, 1/image): scan + classify + sorts + 16-wide NMS ============
__global__ void __launch_bounds__(1024) k_sel(const ull* __restrict__ keys,
                                              const uint16_t* __restrict__ ghist,
                                              const uint32_t* __restrict__ cnts,
                                              const float* __restrict__ pred_boxes,
                                              const float* __restrict__ target_sizes,
                                              float* __restrict__ out) {
    const int img = blockIdx.x;
    const int tid = threadIdx.x;
    const int lane = tid & 63;
    const int wv = tid >> 6;                 // 16 waves

    __shared__ uint32_t hist[TBINS];         // 32 KB (live through continuations)
    __shared__ uint32_t part[1024];          // 4 KB
    __shared__ float4 shPB[NQ];              // 14.4 KB
    __shared__ ull binK[HSEG];               // 8 KB
    __shared__ ull headK[HSEG];              // 8 KB
    __shared__ float aX1[POST], aY1[POST], aX2[POST], aY2[POST], aAr[POST];
    __shared__ int   aCl[POST];
    __shared__ float s_x1[K_WIN], s_y1[K_WIN], s_x2[K_WIN], s_y2[K_WIN];
    __shared__ int   s_cl[K_WIN];
    __shared__ uint32_t s_em[K_WIN];
    __shared__ ull sF0;
    __shared__ uint32_t sCntA, sCntB, sMX;
    __shared__ uint32_t sB1, sTp1, sB2, sTp2, sTK;

    const float ih = target_sizes[img * 2 + 0];
    const float iw = target_sizes[img * 2 + 1];
    const float* pb = pred_boxes + (size_t)img * NQ * 4;

    auto mckey = [&](uint32_t f) -> uint32_t {   // identical arithmetic rounds 0-10
        uint32_t q = qclamp(f / NC);
        float4 bb = shPB[q];
        float x1 = (bb.x - 0.5f * bb.z) * iw;
        float y1 = (bb.y - 0.5f * bb.w) * ih;
        float x2 = (bb.x + 0.5f * bb.z) * iw;
        float y2 = (bb.y + 0.5f * bb.w) * ih;
        return fkey(fmaxf(fmaxf(x1, y1), fmaxf(x2, y2)));
    };

    // ---- P0: shPB, hist = g0+g1 (plain stores) + part, key regs, zero state ----
    if (tid < NQ) shPB[tid] = ((const float4*)pb)[tid];
    binK[tid] = 0ull; headK[tid] = 0ull;
    if (tid == 0) { sCntA = 0u; sCntB = 0u; sMX = 0u; sF0 = 0ull;
                    sB1 = 0u; sTp1 = 1u; sB2 = 0u; sTp2 = 0u; sTK = 0u; }
    {
        const uint16_t* g0 = ghist + (size_t)(img * 2) * TBINS;
        const uint16_t* g1 = g0 + TBINS;
        uint32_t s = 0;
        int b0 = tid * 8;
        #pragma unroll
        for (int j = 0; j < 8; ++j) {
            uint32_t hv = (uint32_t)g0[b0 + j] + (uint32_t)g1[b0 + j];
            hist[b0 + j] = hv;
            s += hv;
        }
        part[tid] = s;
    }
    const uint32_t c0 = cnts[img * 2 + 0];
    const uint32_t c1 = cnts[img * 2 + 1];
    const int total = (int)(c0 + c1);
    const ull* seg0 = keys + (size_t)(img * 2) * CAPH;
    const ull* seg1 = seg0 + CAPH;
    ull kk[NSLOT];
    #pragma unroll
    for (int j = 0; j < NSLOT; ++j) {
        int i = tid + (j << 10);
        ull x = 0ull;
        if (i < total) x = (i < (int)c0) ? seg0[i] : seg1[i - (int)c0];
        kk[j] = x;
    }
    __syncthreads();

    // ---- P1: dual-target scan (B1@TK, B2@T2) ----
    if (tid < 64) {
        uint32_t pv[16]; uint32_t tot = 0;
        #pragma unroll
        for (int j = 0; j < 16; ++j) { pv[j] = part[tid * 16 + j]; tot += pv[j]; }
        uint32_t sinc = tot;
        #pragma unroll
        for (int off = 1; off < 64; off <<= 1) {
            uint32_t o = (uint32_t)__shfl_down((int)sinc, off, 64);
            if (tid + off < 64) sinc += o;
        }
        uint32_t tt = (uint32_t)__shfl((int)sinc, 0, 64);
        uint32_t TKl = (tt < PRE) ? tt : PRE;
        uint32_t T2l = (TKl < HSEG) ? TKl : HSEG;
        if (tid == 0) sTK = TKl;
        uint32_t cum = sinc - tot;
        for (int j = 15; j >= 0; --j) {
            if (cum < TKl && cum + pv[j] >= TKl) {
                int pbn = (tid * 16 + j) * 8;
                uint32_t c2 = cum;
                for (int b = pbn + 7; b >= pbn; --b) {
                    if (c2 + hist[b] >= TKl) { sB1 = (uint32_t)b; sTp1 = TKl - c2; break; }
                    c2 += hist[b];
                }
            }
            if (cum < T2l && cum + pv[j] >= T2l) {
                int pbn = (tid * 16 + j) * 8;
                uint32_t c2 = cum;
                for (int b = pbn + 7; b >= pbn; --b) {
                    if (c2 + hist[b] >= T2l) { sB2 = (uint32_t)b; sTp2 = T2l - c2; break; }
                    c2 += hist[b];
                }
            }
            cum += pv[j];
        }
    }
    __syncthreads();
    const uint32_t B1 = sB1, tp1 = sTp1, B2 = sB2;
    const uint32_t TK = sTK;
    const int C1 = (int)(((TK < (uint32_t)HSEG) ? TK : (uint32_t)HSEG) - sTp2);

    // ---- P2: classify registers: offD part (bin>B1) + binK (==B1) + headK (>B2) ----
    uint32_t lmx = 0u;
    #pragma unroll
    for (int j = 0; j < NSLOT; ++j) {
        ull x = kk[j];
        uint32_t bin = (uint32_t)(x >> 51);
        bool liveK = (x != 0ull);
        if (liveK && bin > B1) { uint32_t km = mckey(~(uint32_t)x); if (km > lmx) lmx = km; }
        bool isA = liveK && (bin == B1);
        bool isB = liveK && (bin > B2);
        ull mA = __ballot(isA);
        if (mA) {
            uint32_t wb = 0u;
            if (lane == 0) wb = atomicAdd(&sCntA, (uint32_t)__popcll(mA));
            wb = (uint32_t)__shfl((int)wb, 0, 64);
            if (isA) {
                uint32_t p = wb + (uint32_t)__popcll(mA & ((1ull << lane) - 1ull));
                if (p < HSEG) binK[p] = x;
            }
        }
        ull mB = __ballot(isB);
        if (mB) {
            uint32_t wb = 0u;
            if (lane == 0) wb = atomicAdd(&sCntB, (uint32_t)__popcll(mB));
            wb = (uint32_t)__shfl((int)wb, 0, 64);
            if (isB) {
                uint32_t p = wb + (uint32_t)__popcll(mB & ((1ull << lane) - 1ull));
                if (p < HSEG) headK[p] = x;
            }
        }
    }
    __syncthreads();

    // ---- P3: DUAL sort (binK: waves 0-3, headK: waves 4-7), desc (verified r7-r10) ----
    {
        ull r0 = 0, r1 = 0, r2 = 0, r3 = 0;
        const int cw = wv & 3;
        const int cb = cw << 8;
        ull* A = (wv < 4) ? binK : headK;
        if (wv < 8) {
            r0 = A[cb | lane]; r1 = A[cb | 64 | lane];
            r2 = A[cb | 128 | lane]; r3 = A[cb | 192 | lane];
            #pragma unroll
            for (int k2 = 2; k2 <= 32; k2 <<= 1) {
                bool d = ((lane & k2) == 0);
                #pragma unroll
                for (int j = 16; j >= 1; j >>= 1) {
                    if (j <= (k2 >> 1)) {
                        bool lw = ((lane & j) == 0);
                        r0 = cex(r0, j, lw, d); r1 = cex(r1, j, lw, d);
                        r2 = cex(r2, j, lw, d); r3 = cex(r3, j, lw, d);
                    }
                }
            }
            #pragma unroll
            for (int j = 32; j >= 1; j >>= 1) {          // k=64
                bool lw = ((lane & j) == 0);
                r0 = cex(r0, j, lw, true);  r1 = cex(r1, j, lw, false);
                r2 = cex(r2, j, lw, true);  r3 = cex(r3, j, lw, false);
            }
            ce(r0, r1, true); ce(r2, r3, false);         // k=128
            #pragma unroll
            for (int j = 32; j >= 1; j >>= 1) {
                bool lw = ((lane & j) == 0);
                r0 = cex(r0, j, lw, true);  r1 = cex(r1, j, lw, true);
                r2 = cex(r2, j, lw, false); r3 = cex(r3, j, lw, false);
            }
            {                                            // k=256
                bool d = ((cw & 1) == 0);
                ce(r0, r2, d); ce(r1, r3, d); ce(r0, r1, d); ce(r2, r3, d);
                #pragma unroll
                for (int j = 32; j >= 1; j >>= 1) {
                    bool lw = ((lane & j) == 0);
                    r0 = cex(r0, j, lw, d); r1 = cex(r1, j, lw, d);
                    r2 = cex(r2, j, lw, d); r3 = cex(r3, j, lw, d);
                }
            }
            A[cb | lane] = r0; A[cb | 64 | lane] = r1;
            A[cb | 128 | lane] = r2; A[cb | 192 | lane] = r3;
        }
        __syncthreads();
        {   // k=512, j=256 cross-chunk
            ull* Bp = (tid >> 9) ? headK : binK;
            int t = tid & 511;
            int i = ((t & ~255) << 1) | (t & 255);
            int ixj = i | 256;
            bool d = ((i & 512) == 0);
            ull a = Bp[i], b = Bp[ixj];
            bool sw = d ? (a < b) : (a > b);
            if (sw) { Bp[i] = b; Bp[ixj] = a; }
        }
        __syncthreads();
        if (wv < 8) {
            r0 = A[cb | lane]; r1 = A[cb | 64 | lane];
            r2 = A[cb | 128 | lane]; r3 = A[cb | 192 | lane];
            bool d = ((cw & 2) == 0);
            ce(r0, r2, d); ce(r1, r3, d); ce(r0, r1, d); ce(r2, r3, d);
            #pragma unroll
            for (int j = 32; j >= 1; j >>= 1) {
                bool lw = ((lane & j) == 0);
                r0 = cex(r0, j, lw, d); r1 = cex(r1, j, lw, d);
                r2 = cex(r2, j, lw, d); r3 = cex(r3, j, lw, d);
            }
            A[cb | lane] = r0; A[cb | 64 | lane] = r1;
            A[cb | 128 | lane] = r2; A[cb | 192 | lane] = r3;
        }
        __syncthreads();
        {   // k=1024, j=512
            ull* Bp = (tid >> 9) ? headK : binK;
            int t = tid & 511;
            ull a = Bp[t], b = Bp[t | 512];
            if (a < b) { Bp[t] = b; Bp[t | 512] = a; }
        }
        __syncthreads();
        {   // k=1024, j=256
            ull* Bp = (tid >> 9) ? headK : binK;
            int t = tid & 511;
            int i = ((t & ~255) << 1) | (t & 255);
            int ixj = i | 256;
            ull a = Bp[i], b = Bp[ixj];
            if (a < b) { Bp[i] = b; Bp[ixj] = a; }
        }
        __syncthreads();
        if (wv < 8) {
            r0 = A[cb | lane]; r1 = A[cb | 64 | lane];
            r2 = A[cb | 128 | lane]; r3 = A[cb | 192 | lane];
            ce(r0, r2, true); ce(r1, r3, true); ce(r0, r1, true); ce(r2, r3, true);
            #pragma unroll
            for (int j = 32; j >= 1; j >>= 1) {
                bool lw = ((lane & j) == 0);
                r0 = cex(r0, j, lw, true); r1 = cex(r1, j, lw, true);
                r2 = cex(r2, j, lw, true); r3 = cex(r3, j, lw, true);
            }
            A[cb | lane] = r0; A[cb | 64 | lane] = r1;
            A[cb | 128 | lane] = r2; A[cb | 192 | lane] = r3;
        }
        __syncthreads();
    }

    // ---- P4: offD = max(sweep lmx, top-tp1 prefix of sorted binK); sF0 ----
    if (tid < (int)tp1) {
        ull x = binK[tid];
        if (x != 0ull) { uint32_t km = mckey(~(uint32_t)x); if (km > lmx) lmx = km; }
    }
    for (int off = 32; off > 0; off >>= 1) {
        uint32_t o = (uint32_t)__shfl_down((int)lmx, off, 64);
        if (o > lmx) lmx = o;
    }
    if (lane == 0) atomicMax(&sMX, lmx);
    if (tid == 0 && C1 > 0) sF0 = headK[0];
    __syncthreads();
    float offD;
    {
        uint32_t m = sMX;
        uint32_t b = (m & 0x80000000u) ? (m & 0x7FFFFFFFu) : ~m;
        offD = __uint_as_float(b) + 1.0f;    // max_coord + 1
    }

    // single-array sort1024 for rare continuation segments (verified r6-r10)
    auto sort1024 = [&]() {
        const int idx = tid;
        ull x = headK[idx];
        #pragma unroll
        for (int k2 = 2; k2 <= 32; k2 <<= 1) {
            bool d = ((lane & k2) == 0);
            #pragma unroll
            for (int j = 16; j >= 1; j >>= 1)
                if (j <= (k2 >> 1)) x = cex(x, j, (lane & j) == 0, d);
        }
        {
            bool d = ((idx & 64) == 0);
            #pragma unroll
            for (int j = 32; j >= 1; j >>= 1) x = cex(x, j, (lane & j) == 0, d);
        }
        for (int k = 128; k <= 1024; k <<= 1) {
            headK[idx] = x;
            __syncthreads();
            for (int j = k >> 1; j >= 64; j >>= 1) {
                if (tid < 512) {
                    int i2 = ((tid & ~(j - 1)) << 1) | (tid & (j - 1));
                    int ixj = i2 | j;
                    ull a = headK[i2], b = headK[ixj];
                    bool sw = ((i2 & k) == 0) ? (a < b) : (a > b);
                    if (sw) { headK[i2] = b; headK[ixj] = a; }
                }
                __syncthreads();
            }
            x = headK[idx];
            bool d = ((idx & k) == 0);
            #pragma unroll
            for (int j = 32; j >= 1; j >>= 1) x = cex(x, j, (lane & j) == 0, d);
        }
        headK[idx] = x;
        __syncthreads();
    };

    // ---- P5: 16-wide lazy windowed greedy NMS (round-9 verified form) ----
    int npick = 0, base = 0, segbase = 0, segend = C1;
    int bcur = (int)B2;
    bool needF0 = (C1 == 0);
    while (npick < POST) {
        if (base >= segend) {
            if (segend >= (int)TK) {   // ranks exhausted: reference repeats index 0
                ull x0 = sF0;
                uint32_t f0 = ~(uint32_t)x0;
                uint32_t u0 = (uint32_t)(x0 >> 32);
                uint32_t q0 = qclamp(f0 / NC);
                uint32_t cc0 = f0 - (f0 / NC) * NC;
                float4 bb = shPB[q0];
                float rx1 = (bb.x - 0.5f * bb.z) * iw;
                float ry1 = (bb.y - 0.5f * bb.w) * ih;
                float rx2 = (bb.x + 0.5f * bb.z) * iw;
                float ry2 = (bb.y + 0.5f * bb.w) * ih;
                float sc = 1.0f / (1.0f + expf(-unkey(u0)));
                for (int p2 = npick + tid; p2 < POST; p2 += 1024) {
                    out[img * POST + p2] = sc;
                    out[BS * POST + img * POST + p2] = (float)cc0;
                    float* ob2 = out + 2 * BS * POST + ((size_t)img * POST + p2) * 4;
                    ob2[0] = rx1; ob2[1] = ry1; ob2[2] = rx2; ob2[3] = ry2;
                }
                break;
            }
            // continuation: next nonempty bin, gather from compacted keys + sort
            while (bcur > 0 && hist[bcur] == 0u) --bcur;
            headK[tid] = 0ull;
            if (tid == 0) sCntA = 0u;
            __syncthreads();
            for (int i0 = 0; i0 < total; i0 += 1024) {
                int i = i0 + tid;
                ull x = 0ull;
                if (i < total) x = (i < (int)c0) ? seg0[i] : seg1[i - (int)c0];
                bool pass = (x != 0ull) && ((uint32_t)(x >> 51) == (uint32_t)bcur);
                ull m = __ballot(pass);
                if (m) {
                    uint32_t wb = 0u;
                    if (lane == 0) wb = atomicAdd(&sCntA, (uint32_t)__popcll(m));
                    wb = (uint32_t)__shfl((int)wb, 0, 64);
                    if (pass) {
                        uint32_t p = wb + (uint32_t)__popcll(m & ((1ull << lane) - 1ull));
                        if (p < HSEG) headK[p] = x;
                    }
                }
            }
            __syncthreads();
            sort1024();
            int avail = (int)((sCntA < (uint32_t)HSEG) ? sCntA : (uint32_t)HSEG);
            int take = (int)TK - segend; if (take > avail) take = avail;
            if (needF0) { if (tid == 0) sF0 = headK[0]; needF0 = false; __syncthreads(); }
            segbase = segend; segend += take; --bcur;
            continue;
        }

        // stage A: wave wv owns candidate rank base+wv
        const int r = base + wv;
        const bool val = (r < segend);
        const ull xk = headK[val ? (r - segbase) : 0];
        const uint32_t f = val ? ~(uint32_t)xk : 0u;
        const uint32_t uk = (uint32_t)(xk >> 32);
        const uint32_t q = qclamp(f / NC);
        const uint32_t cc = f - (f / NC) * NC;
        float4 bb = shPB[q];
        const float x1 = (bb.x - 0.5f * bb.z) * iw;
        const float y1 = (bb.y - 0.5f * bb.w) * ih;
        const float x2 = (bb.x + 0.5f * bb.z) * iw;
        const float y2 = (bb.y + 0.5f * bb.w) * ih;
        if (lane == 0) {
            s_x1[wv] = x1; s_y1[wv] = y1; s_x2[wv] = x2; s_y2[wv] = y2;
            s_cl[wv] = val ? (int)cc : -1;
        }
        __syncthreads();

        // stage B: conflicts (offset arithmetic replicates reference)
        const float o = (float)cc * offD;
        const float cx1 = x1 + o, cy1 = y1 + o, cx2 = x2 + o, cy2 = y2 + o;
        const float car = (cx2 - cx1) * (cy2 - cy1);
        bool cf = false;
        if (val && lane < wv && s_cl[lane] == (int)cc) {
            float jx1 = s_x1[lane] + o, jy1 = s_y1[lane] + o;
            float jx2 = s_x2[lane] + o, jy2 = s_y2[lane] + o;
            float arj = (jx2 - jx1) * (jy2 - jy1);
            float xx1 = fmaxf(jx1, cx1), yy1 = fmaxf(jy1, cy1);
            float xx2 = fminf(jx2, cx2), yy2 = fminf(jy2, cy2);
            float inter = fmaxf(xx2 - xx1, 0.0f) * fmaxf(yy2 - yy1, 0.0f);
            float uni = (arj + car) - inter;
            float iou = inter / fmaxf(uni, 1e-9f);
            cf = !(iou <= 0.7f);
        }
        uint32_t em = (uint32_t)(__ballot(cf) & 0xFFFFull);
        bool pf = false;
        for (int i2 = lane; i2 < npick; i2 += 64) {
            if (aCl[i2] == (int)cc) {
                float jx1 = aX1[i2] + o, jy1 = aY1[i2] + o;
                float jx2 = aX2[i2] + o, jy2 = aY2[i2] + o;
                float arj = aAr[i2];
                float xx1 = fmaxf(jx1, cx1), yy1 = fmaxf(jy1, cy1);
                float xx2 = fminf(jx2, cx2), yy2 = fminf(jy2, cy2);
                float inter = fmaxf(xx2 - xx1, 0.0f) * fmaxf(yy2 - yy1, 0.0f);
                float uni = (arj + car) - inter;
                float iou = inter / fmaxf(uni, 1e-9f);
                pf |= !(iou <= 0.7f);
            }
        }
        bool anyPrior = (__ballot(pf) != 0ull);
        if (lane == 0)
            s_em[wv] = em | (anyPrior ? 0x80000000u : 0u) | (val ? 0u : 0x40000000u);
        __syncthreads();

        // stage C: uniform sequential resolution
        uint32_t acc = 0u; int a = 0;
        const int room = POST - npick;
        #pragma unroll
        for (int w2 = 0; w2 < K_WIN; ++w2) {
            uint32_t ew = s_em[w2];
            if (!(ew & 0xC0000000u) && a < room && ((ew & 0xFFFFu & acc) == 0u)) {
                acc |= (1u << w2); ++a;
            }
        }

        // stage D: accepted waves write output + accepted list
        if (((acc >> wv) & 1u) && lane == 0) {
            int p = npick + __popc(acc & ((1u << wv) - 1u));
            float sc = 1.0f / (1.0f + expf(-unkey(uk)));
            out[img * POST + p] = sc;
            out[BS * POST + img * POST + p] = (float)cc;
            float* ob2 = out + 2 * BS * POST + ((size_t)img * POST + p) * 4;
            ob2[0] = x1; ob2[1] = y1; ob2[2] = x2; ob2[3] = y2;
            aX1[p] = x1; aY1[p] = y1; aX2[p] = x2; aY2[p] = y2;
            aAr[p] = car; aCl[p] = (int)cc;
        }
        npick += a;
        base += K_WIN;
        // next iteration's stage-A barrier orders stage-D writes before stage-B reads
    }
}

extern "C" void kernel_launch(void* const* d_in, const int* in_sizes, int n_in,
                              void* d_out, int out_size, void* d_ws, size_t ws_size,
                              hipStream_t stream) {
    const float* logits = (const float*)d_in[0];
    const float* boxes  = (const float*)d_in[1];
    const float* tsizes = (const float*)d_in[2];
    float* out = (float*)d_out;

    uint32_t* cnts = (uint32_t*)((char*)d_ws + WS_CNT);
    uint16_t* ghist = (uint16_t*)((char*)d_ws + WS_GH);
    ull* keys = (ull*)((char*)d_ws + WS_KEYS);

    k_compact<<<2 * BS, 1024, 0, stream>>>(logits, keys, ghist, cnts);
    k_sel<<<BS, 1024, 0, stream>>>(keys, ghist, cnts, boxes, tsizes, out);
}

// Round 12
// 134.773 us; speedup vs baseline: 1.0902x; 1.0257x over previous
//
#include <hip/hip_runtime.h>
#include <cstdint>

#pragma clang fp contract(off)

#define BS   128
#define NQ   900
#define NC   91
#define NQC  (NQ * NC)   // 81900
#define Q4   (NQC / 4)   // 20475
#define HHALF 10238      // ceil(Q4/2)
#define PRE  10000
#define POST 100
#define TBITS 13
#define TBINS (1 << TBITS)   // 8192
#define TSHIFT (32 - TBITS)  // 19
#define K_WIN 16
#define HSEG 1024
#define KS   2780        // sampled (1/4) suffix-count target (verified rounds 3-11)
#define CAPH 7680        // per-half key capacity (~5.6K expected, >19 sigma margin)
#define NSLOT 15         // ceil(2*CAPH / 1024)

typedef unsigned long long ull;

// ---- workspace ----
#define WS_CNT 0                     // 256 * 4 B
#define WS_GH  4096                  // 256 * 8192 * 2B = 4 MB per-half exact hist
#define WS_KEYS (4096 + 4*1024*1024) // 128 * 2 * 7680 * 8 = 15.73 MB

__device__ __forceinline__ uint32_t fkey(float f) {
    uint32_t b = __float_as_uint(f);
    return (b & 0x80000000u) ? ~b : (b | 0x80000000u);
}
__device__ __forceinline__ float unkey(uint32_t u) {
    uint32_t b = (u & 0x80000000u) ? (u & 0x7FFFFFFFu) : ~u;
    return __uint_as_float(b);
}
__device__ __forceinline__ uint32_t qclamp(uint32_t q) { return (q < NQ) ? q : (NQ - 1); }

__device__ __forceinline__ ull shflx(ull v, int j) {
    uint32_t lo = (uint32_t)__shfl_xor((int)(uint32_t)v, j, 64);
    uint32_t hi = (uint32_t)__shfl_xor((int)(uint32_t)(v >> 32), j, 64);
    return ((ull)hi << 32) | (ull)lo;
}
__device__ __forceinline__ ull cex(ull v, int j, bool lower, bool desc) {
    ull pb = shflx(v, j);
    ull a = lower ? v : pb;
    ull b = lower ? pb : v;
    bool sw = desc ? (a < b) : (a > b);
    return sw ? pb : v;
}
__device__ __forceinline__ void ce(ull& a, ull& b, bool desc) {
    bool sw = desc ? (a < b) : (a > b);
    if (sw) { ull t = a; a = b; b = t; }
}

// ============ Kernel 1 (256 blocks, 2/image): Tlo + compact keys + exact half hist ============
// Compact loop: ONE atomic chain per 4096 elements (16 ballots, accumulated popcounts),
// 4-deep float4 load unroll. Key SET identical to rounds 9-11 (same predicate);
// intra-segment order differs but all consumers sort (unique keys) -> bit-identical output.
__global__ void __launch_bounds__(1024) k_compact(const float* __restrict__ logits,
                                                  ull* __restrict__ keys,
                                                  uint16_t* __restrict__ ghist,
                                                  uint32_t* __restrict__ cnts) {
    const int img = blockIdx.x >> 1;
    const int h = blockIdx.x & 1;
    const int tid = threadIdx.x;
    const int lane = tid & 63;
    __shared__ uint32_t hist[TBINS];   // 32 KB (sampled, then reused for exact)
    __shared__ uint32_t part[1024];
    __shared__ uint32_t sTB, sCnt;
    const float4* lg4 = (const float4*)(logits + (size_t)img * NQC);
    for (int i = tid; i < TBINS; i += 1024) hist[i] = 0u;
    if (tid == 0) sCnt = 0u;
    float4 sv[5];
    #pragma unroll
    for (int c = 0; c < 5; ++c) sv[c] = lg4[c * 4096 + tid];   // max 17407 < 20475
    __syncthreads();
    #pragma unroll
    for (int c = 0; c < 5; ++c) {
        atomicAdd(&hist[fkey(sv[c].x) >> TSHIFT], 1u);
        atomicAdd(&hist[fkey(sv[c].y) >> TSHIFT], 1u);
        atomicAdd(&hist[fkey(sv[c].z) >> TSHIFT], 1u);
        atomicAdd(&hist[fkey(sv[c].w) >> TSHIFT], 1u);
    }
    __syncthreads();
    {
        uint32_t s = 0;
        int b0 = tid * 8;
        #pragma unroll
        for (int j = 0; j < 8; ++j) s += hist[b0 + j];
        part[tid] = s;
    }
    __syncthreads();
    if (tid < 64) {   // wave-0 suffix scan -> Tlo BIN (verified rounds 3-11)
        uint32_t pv[16]; uint32_t tot = 0;
        #pragma unroll
        for (int j = 0; j < 16; ++j) { pv[j] = part[tid * 16 + j]; tot += pv[j]; }
        uint32_t sinc = tot;
        #pragma unroll
        for (int off = 1; off < 64; off <<= 1) {
            uint32_t o = (uint32_t)__shfl_down((int)sinc, off, 64);
            if (tid + off < 64) sinc += o;
        }
        uint32_t cum = sinc - tot;
        for (int j = 15; j >= 0; --j) {
            if (cum < KS && cum + pv[j] >= KS) {
                int pbn = (tid * 16 + j) * 8;
                uint32_t c2 = cum;
                for (int b = pbn + 7; b >= pbn; --b) {
                    if (c2 + hist[b] >= KS) { sTB = (uint32_t)b; break; }
                    c2 += hist[b];
                }
            }
            cum += pv[j];
        }
    }
    __syncthreads();
    const uint32_t TB = sTB;
    // reset hist for exact candidate histogram (only stored keys counted)
    for (int i = tid; i < TBINS; i += 1024) hist[i] = 0u;
    __syncthreads();
    // compact own half's candidates to global segment (order irrelevant)
    ull* seg = keys + (size_t)(img * 2 + h) * CAPH;
    const int lo = h * HHALF;
    const int hi = (lo + HHALF < Q4) ? (lo + HHALF) : Q4;
    for (int i0 = lo; i0 < hi; i0 += 4096) {
        float4 v[4]; bool inb[4]; int ii[4];
        #pragma unroll
        for (int s = 0; s < 4; ++s) {
            int i = i0 + (s << 10) + tid;
            ii[s] = i; inb[s] = (i < hi);
            v[s] = inb[s] ? lg4[i] : make_float4(0.f, 0.f, 0.f, 0.f);
        }
        uint32_t u[16]; bool pass[16];
        #pragma unroll
        for (int s = 0; s < 4; ++s) {
            u[s * 4 + 0] = fkey(v[s].x); u[s * 4 + 1] = fkey(v[s].y);
            u[s * 4 + 2] = fkey(v[s].z); u[s * 4 + 3] = fkey(v[s].w);
            #pragma unroll
            for (int c = 0; c < 4; ++c)
                pass[s * 4 + c] = inb[s] && ((u[s * 4 + c] >> TSHIFT) >= TB);
        }
        ull m[16]; uint32_t pc[16]; uint32_t tot = 0;
        #pragma unroll
        for (int c = 0; c < 16; ++c) {
            m[c] = __ballot(pass[c]);
            pc[c] = (uint32_t)__popcll(m[c]);
            tot += pc[c];
        }
        uint32_t wb = 0u;
        if (lane == 0 && tot) wb = atomicAdd(&sCnt, tot);
        wb = (uint32_t)__shfl((int)wb, 0, 64);
        ull lm = (1ull << lane) - 1ull;
        uint32_t off = 0;
        #pragma unroll
        for (int c = 0; c < 16; ++c) {
            if (pass[c]) {
                uint32_t p = wb + off + (uint32_t)__popcll(m[c] & lm);
                uint32_t fi = (uint32_t)(ii[c >> 2] * 4 + (c & 3));
                if (p < CAPH) {
                    seg[p] = ((ull)u[c] << 32) | (ull)(0xFFFFFFFFu - fi);
                    atomicAdd(&hist[u[c] >> TSHIFT], 1u);
                }
            }
            off += pc[c];
        }
    }
    __syncthreads();
    uint16_t* g = ghist + (size_t)(img * 2 + h) * TBINS;   // bin count <= 40950 < 65536
    for (int i = tid; i < TBINS; i += 1024) g[i] = (uint16_t)hist[i];
    if (tid == 0) cnts[img * 2 + h] = (sCnt < CAPH) ? sCnt : CAPH;
}

// ============ Kernel 2 (128 blocks, 1/image): scan + classify + sorts + 16-wide NMS ============
__global__ void __launch_bounds__(1024) k_sel(const ull* __restrict__ keys,
                                              const uint16_t* __restrict__ ghist,
                                              const uint32_t* __restrict__ cnts,
                                              const float* __restrict__ pred_boxes,
                                              const float* __restrict__ target_sizes,
                                              float* __restrict__ out) {
    const int img = blockIdx.x;
    const int tid = threadIdx.x;
    const int lane = tid & 63;
    const int wv = tid >> 6;                 // 16 waves

    __shared__ uint32_t hist[TBINS];         // 32 KB (live through continuations)
    __shared__ uint32_t part[1024];          // 4 KB (scan scratch; reused in P2)
    __shared__ float4 shPB[NQ];              // 14.4 KB
    __shared__ ull binK[HSEG];               // 8 KB
    __shared__ ull headK[HSEG];              // 8 KB
    __shared__ float aX1[POST], aY1[POST], aX2[POST], aY2[POST], aAr[POST];
    __shared__ int   aCl[POST];
    __shared__ float s_x1[K_WIN], s_y1[K_WIN], s_x2[K_WIN], s_y2[K_WIN];
    __shared__ int   s_cl[K_WIN];
    __shared__ uint32_t s_em[K_WIN];
    __shared__ ull sF0;
    __shared__ uint32_t sCntA, sCntB, sMX;
    __shared__ uint32_t sB1, sTp1, sB2, sTp2, sTK;

    const float ih = target_sizes[img * 2 + 0];
    const float iw = target_sizes[img * 2 + 1];
    const float* pb = pred_boxes + (size_t)img * NQ * 4;

    auto mckey = [&](uint32_t f) -> uint32_t {   // identical arithmetic rounds 0-11
        uint32_t q = qclamp(f / NC);
        float4 bb = shPB[q];
        float x1 = (bb.x - 0.5f * bb.z) * iw;
        float y1 = (bb.y - 0.5f * bb.w) * ih;
        float x2 = (bb.x + 0.5f * bb.z) * iw;
        float y2 = (bb.y + 0.5f * bb.w) * ih;
        return fkey(fmaxf(fmaxf(x1, y1), fmaxf(x2, y2)));
    };

    // ---- P0: shPB, hist = g0+g1 (plain stores) + part, key regs, zero state ----
    if (tid < NQ) shPB[tid] = ((const float4*)pb)[tid];
    binK[tid] = 0ull; headK[tid] = 0ull;
    if (tid == 0) { sCntA = 0u; sCntB = 0u; sMX = 0u; sF0 = 0ull;
                    sB1 = 0u; sTp1 = 1u; sB2 = 0u; sTp2 = 0u; sTK = 0u; }
    {
        const uint16_t* g0 = ghist + (size_t)(img * 2) * TBINS;
        const uint16_t* g1 = g0 + TBINS;
        uint32_t s = 0;
        int b0 = tid * 8;
        #pragma unroll
        for (int j = 0; j < 8; ++j) {
            uint32_t hv = (uint32_t)g0[b0 + j] + (uint32_t)g1[b0 + j];
            hist[b0 + j] = hv;
            s += hv;
        }
        part[tid] = s;
    }
    const uint32_t c0 = cnts[img * 2 + 0];
    const uint32_t c1 = cnts[img * 2 + 1];
    const int total = (int)(c0 + c1);
    const ull* seg0 = keys + (size_t)(img * 2) * CAPH;
    const ull* seg1 = seg0 + CAPH;
    ull kk[NSLOT];
    #pragma unroll
    for (int j = 0; j < NSLOT; ++j) {
        int i = tid + (j << 10);
        ull x = 0ull;
        if (i < total) x = (i < (int)c0) ? seg0[i] : seg1[i - (int)c0];
        kk[j] = x;
    }
    __syncthreads();

    // ---- P1: dual-target scan (B1@TK, B2@T2) ----
    if (tid < 64) {
        uint32_t pv[16]; uint32_t tot = 0;
        #pragma unroll
        for (int j = 0; j < 16; ++j) { pv[j] = part[tid * 16 + j]; tot += pv[j]; }
        uint32_t sinc = tot;
        #pragma unroll
        for (int off = 1; off < 64; off <<= 1) {
            uint32_t o = (uint32_t)__shfl_down((int)sinc, off, 64);
            if (tid + off < 64) sinc += o;
        }
        uint32_t tt = (uint32_t)__shfl((int)sinc, 0, 64);
        uint32_t TKl = (tt < PRE) ? tt : PRE;
        uint32_t T2l = (TKl < HSEG) ? TKl : HSEG;
        if (tid == 0) sTK = TKl;
        uint32_t cum = sinc - tot;
        for (int j = 15; j >= 0; --j) {
            if (cum < TKl && cum + pv[j] >= TKl) {
                int pbn = (tid * 16 + j) * 8;
                uint32_t c2 = cum;
                for (int b = pbn + 7; b >= pbn; --b) {
                    if (c2 + hist[b] >= TKl) { sB1 = (uint32_t)b; sTp1 = TKl - c2; break; }
                    c2 += hist[b];
                }
            }
            if (cum < T2l && cum + pv[j] >= T2l) {
                int pbn = (tid * 16 + j) * 8;
                uint32_t c2 = cum;
                for (int b = pbn + 7; b >= pbn; --b) {
                    if (c2 + hist[b] >= T2l) { sB2 = (uint32_t)b; sTp2 = T2l - c2; break; }
                    c2 += hist[b];
                }
            }
            cum += pv[j];
        }
    }
    __syncthreads();
    const uint32_t B1 = sB1, tp1 = sTp1, B2 = sB2;
    const uint32_t TK = sTK;
    const int C1 = (int)(((TK < (uint32_t)HSEG) ? TK : (uint32_t)HSEG) - sTp2);

    // ---- P2: classify registers, TWO-PASS (zero atomics): offD part (bin>B1) +
    //          binK (==B1) + headK (>B2). part[] reused: [0..15]=A cnt, [16..31]=B cnt,
    //          [32..47]=A base, [48..63]=B base ----
    uint32_t lmx = 0u;
    {
        uint32_t cA = 0u, cB = 0u;
        #pragma unroll
        for (int j = 0; j < NSLOT; ++j) {
            ull x = kk[j];
            uint32_t bin = (uint32_t)(x >> 51);
            bool liveK = (x != 0ull);
            if (liveK && bin > B1) { uint32_t km = mckey(~(uint32_t)x); if (km > lmx) lmx = km; }
            cA += (liveK && bin == B1) ? 1u : 0u;
            cB += (liveK && bin > B2) ? 1u : 0u;
        }
        uint32_t rA = cA, rB = cB;
        #pragma unroll
        for (int off = 32; off > 0; off >>= 1) {
            rA += (uint32_t)__shfl_down((int)rA, off, 64);
            rB += (uint32_t)__shfl_down((int)rB, off, 64);
        }
        if (lane == 0) { part[wv] = rA; part[16 + wv] = rB; }
        __syncthreads();
        if (tid == 0) {
            uint32_t sA = 0u, sB = 0u;
            #pragma unroll
            for (int w = 0; w < 16; ++w) {
                part[32 + w] = sA; sA += part[w];
                part[48 + w] = sB; sB += part[16 + w];
            }
        }
        __syncthreads();
        uint32_t curA = part[32 + wv];
        uint32_t curB = part[48 + wv];
        ull lm = (1ull << lane) - 1ull;
        #pragma unroll
        for (int j = 0; j < NSLOT; ++j) {
            ull x = kk[j];
            uint32_t bin = (uint32_t)(x >> 51);
            bool liveK = (x != 0ull);
            bool isA = liveK && (bin == B1);
            bool isB = liveK && (bin > B2);
            ull mA = __ballot(isA);
            ull mB = __ballot(isB);
            if (isA) {
                uint32_t p = curA + (uint32_t)__popcll(mA & lm);
                if (p < HSEG) binK[p] = x;
            }
            if (isB) {
                uint32_t p = curB + (uint32_t)__popcll(mB & lm);
                if (p < HSEG) headK[p] = x;
            }
            curA += (uint32_t)__popcll(mA);
            curB += (uint32_t)__popcll(mB);
        }
    }
    __syncthreads();

    // ---- P3: DUAL sort (binK: waves 0-3, headK: waves 4-7), desc (verified r7-r11) ----
    {
        ull r0 = 0, r1 = 0, r2 = 0, r3 = 0;
        const int cw = wv & 3;
        const int cb = cw << 8;
        ull* A = (wv < 4) ? binK : headK;
        if (wv < 8) {
            r0 = A[cb | lane]; r1 = A[cb | 64 | lane];
            r2 = A[cb | 128 | lane]; r3 = A[cb | 192 | lane];
            #pragma unroll
            for (int k2 = 2; k2 <= 32; k2 <<= 1) {
                bool d = ((lane & k2) == 0);
                #pragma unroll
                for (int j = 16; j >= 1; j >>= 1) {
                    if (j <= (k2 >> 1)) {
                        bool lw = ((lane & j) == 0);
                        r0 = cex(r0, j, lw, d); r1 = cex(r1, j, lw, d);
                        r2 = cex(r2, j, lw, d); r3 = cex(r3, j, lw, d);
                    }
                }
            }
            #pragma unroll
            for (int j = 32; j >= 1; j >>= 1) {          // k=64
                bool lw = ((lane & j) == 0);
                r0 = cex(r0, j, lw, true);  r1 = cex(r1, j, lw, false);
                r2 = cex(r2, j, lw, true);  r3 = cex(r3, j, lw, false);
            }
            ce(r0, r1, true); ce(r2, r3, false);         // k=128
            #pragma unroll
            for (int j = 32; j >= 1; j >>= 1) {
                bool lw = ((lane & j) == 0);
                r0 = cex(r0, j, lw, true);  r1 = cex(r1, j, lw, true);
                r2 = cex(r2, j, lw, false); r3 = cex(r3, j, lw, false);
            }
            {                                            // k=256
                bool d = ((cw & 1) == 0);
                ce(r0, r2, d); ce(r1, r3, d); ce(r0, r1, d); ce(r2, r3, d);
                #pragma unroll
                for (int j = 32; j >= 1; j >>= 1) {
                    bool lw = ((lane & j) == 0);
                    r0 = cex(r0, j, lw, d); r1 = cex(r1, j, lw, d);
                    r2 = cex(r2, j, lw, d); r3 = cex(r3, j, lw, d);
                }
            }
            A[cb | lane] = r0; A[cb | 64 | lane] = r1;
            A[cb | 128 | lane] = r2; A[cb | 192 | lane] = r3;
        }
        __syncthreads();
        {   // k=512, j=256 cross-chunk
            ull* Bp = (tid >> 9) ? headK : binK;
            int t = tid & 511;
            int i = ((t & ~255) << 1) | (t & 255);
            int ixj = i | 256;
            bool d = ((i & 512) == 0);
            ull a = Bp[i], b = Bp[ixj];
            bool sw = d ? (a < b) : (a > b);
            if (sw) { Bp[i] = b; Bp[ixj] = a; }
        }
        __syncthreads();
        if (wv < 8) {
            r0 = A[cb | lane]; r1 = A[cb | 64 | lane];
            r2 = A[cb | 128 | lane]; r3 = A[cb | 192 | lane];
            bool d = ((cw & 2) == 0);
            ce(r0, r2, d); ce(r1, r3, d); ce(r0, r1, d); ce(r2, r3, d);
            #pragma unroll
            for (int j = 32; j >= 1; j >>= 1) {
                bool lw = ((lane & j) == 0);
                r0 = cex(r0, j, lw, d); r1 = cex(r1, j, lw, d);
                r2 = cex(r2, j, lw, d); r3 = cex(r3, j, lw, d);
            }
            A[cb | lane] = r0; A[cb | 64 | lane] = r1;
            A[cb | 128 | lane] = r2; A[cb | 192 | lane] = r3;
        }
        __syncthreads();
        {   // k=1024, j=512
            ull* Bp = (tid >> 9) ? headK : binK;
            int t = tid & 511;
            ull a = Bp[t], b = Bp[t | 512];
            if (a < b) { Bp[t] = b; Bp[t | 512] = a; }
        }
        __syncthreads();
        {   // k=1024, j=256
            ull* Bp = (tid >> 9) ? headK : binK;
            int t = tid & 511;
            int i = ((t & ~255) << 1) | (t & 255);
            int ixj = i | 256;
            ull a = Bp[i], b = Bp[ixj];
            if (a < b) { Bp[i] = b; Bp[ixj] = a; }
        }
        __syncthreads();
        if (wv < 8) {
            r0 = A[cb | lane]; r1 = A[cb | 64 | lane];
            r2 = A[cb | 128 | lane]; r3 = A[cb | 192 | lane];
            ce(r0, r2, true); ce(r1, r3, true); ce(r0, r1, true); ce(r2, r3, true);
            #pragma unroll
            for (int j = 32; j >= 1; j >>= 1) {
                bool lw = ((lane & j) == 0);
                r0 = cex(r0, j, lw, true); r1 = cex(r1, j, lw, true);
                r2 = cex(r2, j, lw, true); r3 = cex(r3, j, lw, true);
            }
            A[cb | lane] = r0; A[cb | 64 | lane] = r1;
            A[cb | 128 | lane] = r2; A[cb | 192 | lane] = r3;
        }
        __syncthreads();
    }

    // ---- P4: offD = max(sweep lmx, top-tp1 prefix of sorted binK); sF0 ----
    if (tid < (int)tp1) {
        ull x = binK[tid];
        if (x != 0ull) { uint32_t km = mckey(~(uint32_t)x); if (km > lmx) lmx = km; }
    }
    for (int off = 32; off > 0; off >>= 1) {
        uint32_t o = (uint32_t)__shfl_down((int)lmx, off, 64);
        if (o > lmx) lmx = o;
    }
    if (lane == 0) atomicMax(&sMX, lmx);
    if (tid == 0 && C1 > 0) sF0 = headK[0];
    __syncthreads();
    float offD;
    {
        uint32_t m = sMX;
        uint32_t b = (m & 0x80000000u) ? (m & 0x7FFFFFFFu) : ~m;
        offD = __uint_as_float(b) + 1.0f;    // max_coord + 1
    }

    // single-array sort1024 for rare continuation segments (verified r6-r11)
    auto sort1024 = [&]() {
        const int idx = tid;
        ull x = headK[idx];
        #pragma unroll
        for (int k2 = 2; k2 <= 32; k2 <<= 1) {
            bool d = ((lane & k2) == 0);
            #pragma unroll
            for (int j = 16; j >= 1; j >>= 1)
                if (j <= (k2 >> 1)) x = cex(x, j, (lane & j) == 0, d);
        }
        {
            bool d = ((idx & 64) == 0);
            #pragma unroll
            for (int j = 32; j >= 1; j >>= 1) x = cex(x, j, (lane & j) == 0, d);
        }
        for (int k = 128; k <= 1024; k <<= 1) {
            headK[idx] = x;
            __syncthreads();
            for (int j = k >> 1; j >= 64; j >>= 1) {
                if (tid < 512) {
                    int i2 = ((tid & ~(j - 1)) << 1) | (tid & (j - 1));
                    int ixj = i2 | j;
                    ull a = headK[i2], b = headK[ixj];
                    bool sw = ((i2 & k) == 0) ? (a < b) : (a > b);
                    if (sw) { headK[i2] = b; headK[ixj] = a; }
                }
                __syncthreads();
            }
            x = headK[idx];
            bool d = ((idx & k) == 0);
            #pragma unroll
            for (int j = 32; j >= 1; j >>= 1) x = cex(x, j, (lane & j) == 0, d);
        }
        headK[idx] = x;
        __syncthreads();
    };

    // ---- P5: 16-wide lazy windowed greedy NMS (round-9 verified form) ----
    int npick = 0, base = 0, segbase = 0, segend = C1;
    int bcur = (int)B2;
    bool needF0 = (C1 == 0);
    while (npick < POST) {
        if (base >= segend) {
            if (segend >= (int)TK) {   // ranks exhausted: reference repeats index 0
                ull x0 = sF0;
                uint32_t f0 = ~(uint32_t)x0;
                uint32_t u0 = (uint32_t)(x0 >> 32);
                uint32_t q0 = qclamp(f0 / NC);
                uint32_t cc0 = f0 - (f0 / NC) * NC;
                float4 bb = shPB[q0];
                float rx1 = (bb.x - 0.5f * bb.z) * iw;
                float ry1 = (bb.y - 0.5f * bb.w) * ih;
                float rx2 = (bb.x + 0.5f * bb.z) * iw;
                float ry2 = (bb.y + 0.5f * bb.w) * ih;
                float sc = 1.0f / (1.0f + expf(-unkey(u0)));
                for (int p2 = npick + tid; p2 < POST; p2 += 1024) {
                    out[img * POST + p2] = sc;
                    out[BS * POST + img * POST + p2] = (float)cc0;
                    float* ob2 = out + 2 * BS * POST + ((size_t)img * POST + p2) * 4;
                    ob2[0] = rx1; ob2[1] = ry1; ob2[2] = rx2; ob2[3] = ry2;
                }
                break;
            }
            // continuation: next nonempty bin, gather from compacted keys + sort
            while (bcur > 0 && hist[bcur] == 0u) --bcur;
            headK[tid] = 0ull;
            if (tid == 0) sCntA = 0u;
            __syncthreads();
            for (int i0 = 0; i0 < total; i0 += 1024) {
                int i = i0 + tid;
                ull x = 0ull;
                if (i < total) x = (i < (int)c0) ? seg0[i] : seg1[i - (int)c0];
                bool pass = (x != 0ull) && ((uint32_t)(x >> 51) == (uint32_t)bcur);
                ull m = __ballot(pass);
                if (m) {
                    uint32_t wb = 0u;
                    if (lane == 0) wb = atomicAdd(&sCntA, (uint32_t)__popcll(m));
                    wb = (uint32_t)__shfl((int)wb, 0, 64);
                    if (pass) {
                        uint32_t p = wb + (uint32_t)__popcll(m & ((1ull << lane) - 1ull));
                        if (p < HSEG) headK[p] = x;
                    }
                }
            }
            __syncthreads();
            sort1024();
            int avail = (int)((sCntA < (uint32_t)HSEG) ? sCntA : (uint32_t)HSEG);
            int take = (int)TK - segend; if (take > avail) take = avail;
            if (needF0) { if (tid == 0) sF0 = headK[0]; needF0 = false; __syncthreads(); }
            segbase = segend; segend += take; --bcur;
            continue;
        }

        // stage A: wave wv owns candidate rank base+wv
        const int r = base + wv;
        const bool val = (r < segend);
        const ull xk = headK[val ? (r - segbase) : 0];
        const uint32_t f = val ? ~(uint32_t)xk : 0u;
        const uint32_t uk = (uint32_t)(xk >> 32);
        const uint32_t q = qclamp(f / NC);
        const uint32_t cc = f - (f / NC) * NC;
        float4 bb = shPB[q];
        const float x1 = (bb.x - 0.5f * bb.z) * iw;
        const float y1 = (bb.y - 0.5f * bb.w) * ih;
        const float x2 = (bb.x + 0.5f * bb.z) * iw;
        const float y2 = (bb.y + 0.5f * bb.w) * ih;
        if (lane == 0) {
            s_x1[wv] = x1; s_y1[wv] = y1; s_x2[wv] = x2; s_y2[wv] = y2;
            s_cl[wv] = val ? (int)cc : -1;
        }
        __syncthreads();

        // stage B: conflicts (offset arithmetic replicates reference)
        const float o = (float)cc * offD;
        const float cx1 = x1 + o, cy1 = y1 + o, cx2 = x2 + o, cy2 = y2 + o;
        const float car = (cx2 - cx1) * (cy2 - cy1);
        bool cf = false;
        if (val && lane < wv && s_cl[lane] == (int)cc) {
            float jx1 = s_x1[lane] + o, jy1 = s_y1[lane] + o;
            float jx2 = s_x2[lane] + o, jy2 = s_y2[lane] + o;
            float arj = (jx2 - jx1) * (jy2 - jy1);
            float xx1 = fmaxf(jx1, cx1), yy1 = fmaxf(jy1, cy1);
            float xx2 = fminf(jx2, cx2), yy2 = fminf(jy2, cy2);
            float inter = fmaxf(xx2 - xx1, 0.0f) * fmaxf(yy2 - yy1, 0.0f);
            float uni = (arj + car) - inter;
            float iou = inter / fmaxf(uni, 1e-9f);
            cf = !(iou <= 0.7f);
        }
        uint32_t em = (uint32_t)(__ballot(cf) & 0xFFFFull);
        bool pf = false;
        for (int i2 = lane; i2 < npick; i2 += 64) {
            if (aCl[i2] == (int)cc) {
                float jx1 = aX1[i2] + o, jy1 = aY1[i2] + o;
                float jx2 = aX2[i2] + o, jy2 = aY2[i2] + o;
                float arj = aAr[i2];
                float xx1 = fmaxf(jx1, cx1), yy1 = fmaxf(jy1, cy1);
                float xx2 = fminf(jx2, cx2), yy2 = fminf(jy2, cy2);
                float inter = fmaxf(xx2 - xx1, 0.0f) * fmaxf(yy2 - yy1, 0.0f);
                float uni = (arj + car) - inter;
                float iou = inter / fmaxf(uni, 1e-9f);
                pf |= !(iou <= 0.7f);
            }
        }
        bool anyPrior = (__ballot(pf) != 0ull);
        if (lane == 0)
            s_em[wv] = em | (anyPrior ? 0x80000000u : 0u) | (val ? 0u : 0x40000000u);
        __syncthreads();

        // stage C: uniform sequential resolution
        uint32_t acc = 0u; int a = 0;
        const int room = POST - npick;
        #pragma unroll
        for (int w2 = 0; w2 < K_WIN; ++w2) {
            uint32_t ew = s_em[w2];
            if (!(ew & 0xC0000000u) && a < room && ((ew & 0xFFFFu & acc) == 0u)) {
                acc |= (1u << w2); ++a;
            }
        }

        // stage D: accepted waves write output + accepted list
        if (((acc >> wv) & 1u) && lane == 0) {
            int p = npick + __popc(acc & ((1u << wv) - 1u));
            float sc = 1.0f / (1.0f + expf(-unkey(uk)));
            out[img * POST + p] = sc;
            out[BS * POST + img * POST + p] = (float)cc;
            float* ob2 = out + 2 * BS * POST + ((size_t)img * POST + p) * 4;
            ob2[0] = x1; ob2[1] = y1; ob2[2] = x2; ob2[3] = y2;
            aX1[p] = x1; aY1[p] = y1; aX2[p] = x2; aY2[p] = y2;
            aAr[p] = car; aCl[p] = (int)cc;
        }
        npick += a;
        base += K_WIN;
        // next iteration's stage-A barrier orders stage-D writes before stage-B reads
    }
}

extern "C" void kernel_launch(void* const* d_in, const int* in_sizes, int n_in,
                              void* d_out, int out_size, void* d_ws, size_t ws_size,
                              hipStream_t stream) {
    const float* logits = (const float*)d_in[0];
    const float* boxes  = (const float*)d_in[1];
    const float* tsizes = (const float*)d_in[2];
    float* out = (float*)d_out;

    uint32_t* cnts = (uint32_t*)((char*)d_ws + WS_CNT);
    uint16_t* ghist = (uint16_t*)((char*)d_ws + WS_GH);
    ull* keys = (ull*)((char*)d_ws + WS_KEYS);

    k_compact<<<2 * BS, 1024, 0, stream>>>(logits, keys, ghist, cnts);
    k_sel<<<BS, 1024, 0, stream>>>(keys, ghist, cnts, boxes, tsizes, out);
}